// Round 5
// baseline (92.044 us; speedup 1.0000x reference)
//
#include <hip/hip_runtime.h>

#define S 2048
#define B 2
#define H 1024
#define NH 16
#define HD 64
#define THREE_H 3072
#define ROWS (S*B)   // 4096

typedef __attribute__((ext_vector_type(8))) short short8;
typedef __attribute__((ext_vector_type(4))) float f32x4;
typedef const __attribute__((address_space(1))) unsigned int* gptr_t;
typedef __attribute__((address_space(3))) unsigned int* lptr_t;

#define N8_A (ROWS * H / 8)        // 524288
#define N8_W (THREE_H * H / 8)     // 393216

__device__ __forceinline__ ushort f2bf(float f) {
    union { float f; unsigned u; } v; v.f = f;
    unsigned r = v.u + 0x7fffu + ((v.u >> 16) & 1u);
    return (ushort)(r >> 16);
}
__device__ __forceinline__ float bf2f(ushort u) {
    union { unsigned u; float f; } v; v.u = ((unsigned)u) << 16;
    return v.f;
}

// ---------------------------------------------------------------------------
// Cast f32 -> bf16 for A and W in one launch
// ---------------------------------------------------------------------------
__global__ void cast_both(const float* __restrict__ A, const float* __restrict__ W,
                          ushort* __restrict__ Ab, ushort* __restrict__ Wb) {
    int i = blockIdx.x * 256 + threadIdx.x;
    const float4* s4;
    ushort* dst;
    if (i < N8_A) { s4 = (const float4*)A; dst = Ab; }
    else if (i < N8_A + N8_W) { s4 = (const float4*)W; dst = Wb; i -= N8_A; }
    else return;
    float4 a = s4[2 * i], b = s4[2 * i + 1];
    short8 o;
    o[0] = f2bf(a.x); o[1] = f2bf(a.y); o[2] = f2bf(a.z); o[3] = f2bf(a.w);
    o[4] = f2bf(b.x); o[5] = f2bf(b.y); o[6] = f2bf(b.z); o[7] = f2bf(b.w);
    *(short8*)(dst + 8 * (size_t)i) = o;
}

// ---------------------------------------------------------------------------
// K1: bf16 MFMA GEMM. Outputs: Qb [bh][s][d] bf16 (direct scatter);
// Kt, Vraw [bh][d][t] bf16 via de-interleaved LDS repack + coalesced stores.
// Each 64-col segment of the 128-col window is exactly one (h, q/k/v) seg.
// ---------------------------------------------------------------------------
__global__ __launch_bounds__(256) void qkv_gemm_mfma(const ushort* __restrict__ Abf,
                                                     const ushort* __restrict__ Wbf,
                                                     const float* __restrict__ bias,
                                                     ushort* __restrict__ Qb,
                                                     ushort* __restrict__ Kt,
                                                     ushort* __restrict__ Vraw) {
    __shared__ ushort Abuf[128 * 32];   // 8 KB
    __shared__ ushort Bbuf[128 * 32];   // 8 KB
    __shared__ ushort Ct[64][136];      // 17 KB epilogue repack (2-way-free banks)
    const int tid = threadIdx.x;
    const int wave = tid >> 6, lane = tid & 63;
    const int wr = wave >> 1, wc = wave & 1;
    const int row0 = blockIdx.x * 128;
    const int col0 = blockIdx.y * 128;

    f32x4 acc[4][4] = {};

    const int lrow = lane >> 2;        // 0..15
    const int lk   = (lane & 3) * 8;   // 0,8,16,24

    for (int k0 = 0; k0 < H; k0 += 32) {
#pragma unroll
        for (int p = 0; p < 2; ++p) {
            int c = wave * 2 + p;
            int row = c * 16 + lrow;
            __builtin_amdgcn_global_load_lds(
                (gptr_t)&Abf[(size_t)(row0 + row) * H + k0 + lk],
                (lptr_t)&Abuf[c * 512 + lane * 8], 16, 0, 0);
            __builtin_amdgcn_global_load_lds(
                (gptr_t)&Wbf[(size_t)(col0 + row) * H + k0 + lk],
                (lptr_t)&Bbuf[c * 512 + lane * 8], 16, 0, 0);
        }
        __syncthreads();

        short8 af[4], bfr[4];
#pragma unroll
        for (int m = 0; m < 4; ++m) {
            int ar = wr * 64 + m * 16 + (lane & 15);
            af[m] = *(const short8*)&Abuf[ar * 32 + (lane >> 4) * 8];
            int br = wc * 64 + m * 16 + (lane & 15);
            bfr[m] = *(const short8*)&Bbuf[br * 32 + (lane >> 4) * 8];
        }
#pragma unroll
        for (int m = 0; m < 4; ++m)
#pragma unroll
            for (int n = 0; n < 4; ++n)
                acc[m][n] = __builtin_amdgcn_mfma_f32_16x16x32_bf16(af[m], bfr[n], acc[m][n], 0, 0, 0);
        __syncthreads();
    }

    // ---- epilogue: two 64-col segments, each uniform (h, sel) ----
    const int il = lane & 15, g = lane >> 4;
    const int t_base = row0 >> 1;   // 64 sequence positions per block
#pragma unroll
    for (int sg = 0; sg < 2; ++sg) {
        int cseg = col0 + sg * 64;
        int h = cseg / 192, rem = cseg % 192;
        int sel = rem >> 6;                    // block-uniform
        if (sel == 0) {
            if (wc == sg) {
#pragma unroll
                for (int n = 0; n < 4; ++n) {
                    int d = n * 16 + il;
                    float bv = bias[cseg + d];
#pragma unroll
                    for (int m = 0; m < 4; ++m) {
                        int rowb = row0 + wr * 64 + m * 16 + g * 4;
#pragma unroll
                        for (int j = 0; j < 4; ++j) {
                            int r = rowb + j;
                            int s = r >> 1, b = r & 1;
                            Qb[((size_t)((b * NH + h) * S + s)) * HD + d] =
                                f2bf(acc[m][n][j] + bv);
                        }
                    }
                }
            }
        } else {
            ushort* dst = (sel == 1) ? Kt : Vraw;
            __syncthreads();
            if (wc == sg) {
#pragma unroll
                for (int n = 0; n < 4; ++n) {
                    int c = n * 16 + il;
                    float bv = bias[cseg + c];
#pragma unroll
                    for (int m = 0; m < 4; ++m) {
                        int t0 = wr * 32 + m * 8 + g * 2;   // even, local t
                        uint lo = (uint)f2bf(acc[m][n][0] + bv) |
                                  ((uint)f2bf(acc[m][n][2] + bv) << 16);
                        uint hi = (uint)f2bf(acc[m][n][1] + bv) |
                                  ((uint)f2bf(acc[m][n][3] + bv) << 16);
                        *(uint*)&Ct[c][t0]      = lo;   // b=0 rows
                        *(uint*)&Ct[c][64 + t0] = hi;   // b=1 rows
                    }
                }
            }
            __syncthreads();
            {
                int c = tid >> 2, sub = tid & 3, b = sub >> 1, th = (sub & 1) * 32;
                ushort* op = dst + ((size_t)((b * NH + h) * HD + c)) * S + t_base + th;
                const ushort* sp = &Ct[c][b * 64 + th];
#pragma unroll
                for (int q = 0; q < 4; ++q)
                    *(short8*)(op + q * 8) = *(const short8*)(sp + q * 8);
            }
        }
    }
}

// ---------------------------------------------------------------------------
// V-suffix scan on Vraw [bh][d][t] bf16: t-contiguous 64B per thread.
// Phase 1: chunk sums (64 chunks x 32 t). Phase 2: tail from csum + in-place.
// ---------------------------------------------------------------------------
__global__ void vsuf_chunksum(const ushort* __restrict__ Vraw, float* __restrict__ csum) {
    int idx = blockIdx.x * 256 + threadIdx.x;   // 131072
    int col = idx & 2047;                        // bh*64 + d
    int chunk = idx >> 11;                       // 0..63
    const ushort* vp = Vraw + (size_t)col * S + chunk * 32;
    float s = 0.f;
#pragma unroll
    for (int q = 0; q < 4; ++q) {
        short8 v = *(const short8*)(vp + q * 8);
#pragma unroll
        for (int k = 0; k < 8; ++k) s += bf2f((ushort)v[k]);
    }
    csum[chunk * 2048 + col] = s;
}

__global__ void vsuf_final(ushort* __restrict__ Vraw, const float* __restrict__ csum) {
    int idx = blockIdx.x * 256 + threadIdx.x;
    int col = idx & 2047;
    int chunk = idx >> 11;
    float acc = 0.f;
    for (int c = chunk + 1; c < 64; ++c) acc += csum[c * 2048 + col];
    ushort* vp = Vraw + (size_t)col * S + chunk * 32;
    float v[32];
#pragma unroll
    for (int q = 0; q < 4; ++q) {
        short8 x = *(const short8*)(vp + q * 8);
#pragma unroll
        for (int k = 0; k < 8; ++k) v[q * 8 + k] = bf2f((ushort)x[k]);
    }
#pragma unroll
    for (int tt = 31; tt >= 0; --tt) { acc += v[tt]; v[tt] = acc; }
#pragma unroll
    for (int q = 0; q < 4; ++q) {
        short8 o;
#pragma unroll
        for (int k = 0; k < 8; ++k) o[k] = f2bf(v[q * 8 + k]);
        *(short8*)(vp + q * 8) = o;
    }
}

// ---------------------------------------------------------------------------
// K3: M[i][j] = sum_t Kt[i][t]*Vsuf[j][t] via MFMA. 16 k-slices of 128 t.
// ---------------------------------------------------------------------------
__global__ __launch_bounds__(256) void kvm_mfma(const ushort* __restrict__ Kt,
                                                const ushort* __restrict__ Vt,
                                                float* __restrict__ Mpart) {
    const int bh = blockIdx.x, kb = blockIdx.y;
    const int tid = threadIdx.x, wave = tid >> 6, lane = tid & 63;
    const int slice = kb * 4 + wave;
    const ushort* Kp = Kt + (size_t)bh * HD * S;
    const ushort* Vp = Vt + (size_t)bh * HD * S;
    f32x4 acc[4][4] = {};
    const int il = lane & 15;
    const int tbase = slice * 128 + (lane >> 4) * 8;
#pragma unroll
    for (int ks = 0; ks < 4; ++ks) {
        const int t = tbase + ks * 32;
        short8 af[4], bfv[4];
#pragma unroll
        for (int m = 0; m < 4; ++m) af[m]  = *(const short8*)&Kp[(size_t)(m * 16 + il) * S + t];
#pragma unroll
        for (int n = 0; n < 4; ++n) bfv[n] = *(const short8*)&Vp[(size_t)(n * 16 + il) * S + t];
#pragma unroll
        for (int m = 0; m < 4; ++m)
#pragma unroll
            for (int n = 0; n < 4; ++n)
                acc[m][n] = __builtin_amdgcn_mfma_f32_16x16x32_bf16(af[m], bfv[n], acc[m][n], 0, 0, 0);
    }
    float* Mp = Mpart + ((size_t)slice * 32 + bh) * 4096;
#pragma unroll
    for (int m = 0; m < 4; ++m)
#pragma unroll
        for (int n = 0; n < 4; ++n)
#pragma unroll
            for (int j = 0; j < 4; ++j) {
                int i  = m * 16 + (lane >> 4) * 4 + j;
                int jj = n * 16 + il;
                Mp[i * 64 + jj] = acc[m][n][j];
            }
}

// ---------------------------------------------------------------------------
// K4: out = scale * Q·M via MFMA; folds the 16-slice Mpart reduce.
// ---------------------------------------------------------------------------
__global__ __launch_bounds__(256) void qm_mfma(const ushort* __restrict__ Qb,
                                               const float* __restrict__ Mpart,
                                               float* __restrict__ out) {
    __shared__ ushort Mt[64][72];   // Mt[d][i] = M[i][d], bf16
    const int bh = blockIdx.x, b = bh >> 4, h = bh & 15;
    const int tid = threadIdx.x;
    {
        const int i = tid >> 2, jq = (tid & 3) * 16;
        f32x4 s0 = {}, s1 = {}, s2 = {}, s3 = {};
#pragma unroll
        for (int sl = 0; sl < 16; ++sl) {
            const float* p = Mpart + ((size_t)sl * 32 + bh) * 4096 + i * 64 + jq;
            s0 += *(const f32x4*)(p);
            s1 += *(const f32x4*)(p + 4);
            s2 += *(const f32x4*)(p + 8);
            s3 += *(const f32x4*)(p + 12);
        }
#pragma unroll
        for (int k = 0; k < 4; ++k) {
            Mt[jq + 0  + k][i] = f2bf(s0[k]);
            Mt[jq + 4  + k][i] = f2bf(s1[k]);
            Mt[jq + 8  + k][i] = f2bf(s2[k]);
            Mt[jq + 12 + k][i] = f2bf(s3[k]);
        }
    }
    __syncthreads();
    const int wave = tid >> 6, lane = tid & 63;
    const int sl15 = lane & 15, koct = (lane >> 4) * 8;
    const int s0b = blockIdx.y * 256 + wave * 64;
    f32x4 acc[4][4] = {};
#pragma unroll
    for (int ks = 0; ks < 2; ++ks) {
        short8 af[4], bfv[4];
#pragma unroll
        for (int m = 0; m < 4; ++m) {
            int s = s0b + m * 16 + sl15;
            af[m] = *(const short8*)&Qb[((size_t)bh * S + s) * HD + ks * 32 + koct];
        }
#pragma unroll
        for (int n = 0; n < 4; ++n)
            bfv[n] = *(const short8*)&Mt[n * 16 + sl15][ks * 32 + koct];
#pragma unroll
        for (int m = 0; m < 4; ++m)
#pragma unroll
            for (int n = 0; n < 4; ++n)
                acc[m][n] = __builtin_amdgcn_mfma_f32_16x16x32_bf16(af[m], bfv[n], acc[m][n], 0, 0, 0);
    }
    const float scale = 0.125f * 0.02209708691207961f;  // HD^-0.5 * S^-0.5
#pragma unroll
    for (int m = 0; m < 4; ++m)
#pragma unroll
        for (int n = 0; n < 4; ++n)
#pragma unroll
            for (int j = 0; j < 4; ++j) {
                int s = s0b + m * 16 + (lane >> 4) * 4 + j;
                int d = n * 16 + sl15;
                out[(size_t)(s * B + b) * H + h * 64 + d] = acc[m][n][j] * scale;
            }
}

// ---------------------------------------------------------------------------
extern "C" void kernel_launch(void* const* d_in, const int* in_sizes, int n_in,
                              void* d_out, int out_size, void* d_ws, size_t ws_size,
                              hipStream_t stream) {
    const float* hidden = (const float*)d_in[0];
    const float* W      = (const float*)d_in[1];
    const float* bias   = (const float*)d_in[2];
    float* out = (float*)d_out;

    ushort* Qb    = (ushort*)d_ws;                      //  8 MB  [bh][s][d] bf16
    ushort* Kt    = Qb + 4194304;                       //  8 MB  [bh][d][t] bf16
    ushort* Vraw  = Kt + 4194304;                       //  8 MB  [bh][d][t] bf16 (scan in place)
    float*  csum  = (float*)(Vraw + 4194304);           // 0.5 MB [chunk][col]
    float*  Mpart = csum + 131072;                      //  8 MB  [16][bh][64][64]
    ushort* Abf   = (ushort*)(Mpart + 2097152);         //  8 MB
    ushort* Wbf   = Abf + 4194304;                      //  6 MB
    // total ~46.5 MB of d_ws

    cast_both<<<(N8_A + N8_W + 255) / 256, 256, 0, stream>>>(hidden, W, Abf, Wbf);
    qkv_gemm_mfma<<<dim3(ROWS / 128, THREE_H / 128), 256, 0, stream>>>(Abf, Wbf, bias, Qb, Kt, Vraw);
    vsuf_chunksum<<<512, 256, 0, stream>>>(Vraw, csum);
    vsuf_final<<<512, 256, 0, stream>>>(Vraw, csum);
    kvm_mfma<<<dim3(32, 4), 256, 0, stream>>>(Kt, Vraw, Mpart);
    qm_mfma<<<dim3(32, 8), 256, 0, stream>>>(Qb, Mpart, out);
}